// Round 18
// baseline (3540.429 us; speedup 1.0000x reference)
//
#include <hip/hip_runtime.h>

typedef _Float16 f16;
typedef _Float16 h2 __attribute__((ext_vector_type(2)));
typedef _Float16 h8 __attribute__((ext_vector_type(8)));
typedef float f4 __attribute__((ext_vector_type(4)));

constexpr int Bb = 64, Tt = 2048, Xx = 128, Hh = 256, G4 = 1024, Z2 = 128;

__device__ __forceinline__ float fdot2f(h2 a, h2 b, float c) {
#if __has_builtin(__builtin_amdgcn_fdot2)
  return __builtin_amdgcn_fdot2(a, b, c, false);
#else
  return c + (float)a[0] * (float)b[0] + (float)a[1] * (float)b[1];
#endif
}
__device__ __forceinline__ float tanhf_(float x) {
  float e = __expf(2.0f * x);
  return 1.0f - 2.0f * __builtin_amdgcn_rcpf(e + 1.0f);
}
__device__ __forceinline__ h2 bch2(unsigned int u) { return __builtin_bit_cast(h2, u); }

template <int CTRL>
__device__ __forceinline__ float qb(float v) {  // quad_perm shuffle
  return __builtin_bit_cast(float,
      __builtin_amdgcn_mov_dpp(__builtin_bit_cast(int, v), CTRL, 0xf, 0xf, true));
}

// ---------------- casts ----------------
__global__ void cast_f16_k(const float* __restrict__ in, f16* __restrict__ out, int n) {
  int i = (blockIdx.x * 256 + threadIdx.x) * 4;
  if (i >= n) return;
  float4 v = *(const float4*)(in + i);
  h2 a = {(f16)v.x, (f16)v.y};
  h2 b = {(f16)v.z, (f16)v.w};
  uint2 o = {__builtin_bit_cast(unsigned int, a), __builtin_bit_cast(unsigned int, b)};
  *(uint2*)(out + i) = o;
}

// Wi columns permuted to quad-gate order col' = 4j+g (orig col = g*256+j).
__global__ void cast_wiP_k(const float* __restrict__ Wi, f16* __restrict__ out) {
  int idx = blockIdx.x * 256 + threadIdx.x;  // 131072 = 128*1024
  int k = idx >> 10, cp = idx & 1023;
  out[idx] = (f16)Wi[(long)k * G4 + (cp & 3) * 256 + (cp >> 2)];
}
__global__ void cast_bhp_k(const float* __restrict__ bh, float* __restrict__ bhp) {
  int cp = blockIdx.x * 256 + threadIdx.x;   // 1024
  bhp[cp] = bh[(cp & 3) * 256 + (cp >> 2)];
}

// v512-layout (control): thread tid owns packed cols c0=2tid, c1=2tid+1.
// Slots: [0,96) c0 k<192; [96,192) c1 k<192; [192,224) c0 tail; [224,256) c1.
__global__ void cast_whT2_k(const float* __restrict__ Wh, f16* __restrict__ WhT2) {
  int idx = blockIdx.x * 256 + threadIdx.x;  // 262144 = 512 threads * 512 f16
  int tid = idx >> 9, f = idx & 511;
  int s = f >> 1, e = f & 1;
  int c_off, k;
  if (s < 96)      { c_off = 0; k = 2 * s + e; }
  else if (s < 192){ c_off = 1; k = 2 * (s - 96) + e; }
  else if (s < 224){ c_off = 0; k = 192 + 2 * (s - 192) + e; }
  else             { c_off = 1; k = 192 + 2 * (s - 224) + e; }
  int cc = 2 * tid + c_off;
  int j = cc >> 2, g = cc & 3;
  WhT2[(long)tid * 512 + f] = (f16)Wh[(long)k * G4 + g * 256 + j];
}

// v512a-layout: bigger reg head. Slots: [0,112) c0 k<224; [112,224) c1 k<224;
// [224,240) c0 tail k in [224,256); [240,256) c1 tail.
__global__ void cast_whA_k(const float* __restrict__ Wh, f16* __restrict__ WhA) {
  int idx = blockIdx.x * 256 + threadIdx.x;  // 262144 = 512 threads * 512 f16
  int tid = idx >> 9, f = idx & 511;
  int s = f >> 1, e = f & 1;
  int c_off, k2;
  if (s < 112)      { c_off = 0; k2 = s; }
  else if (s < 224) { c_off = 1; k2 = s - 112; }
  else if (s < 240) { c_off = 0; k2 = 112 + (s - 224); }
  else              { c_off = 1; k2 = 112 + (s - 240); }
  int k = 2 * k2 + e;
  int cc = 2 * tid + c_off;
  int j = cc >> 2, g = cc & 3;
  WhA[(long)tid * 512 + f] = (f16)Wh[(long)k * G4 + g * 256 + j];
}

// ---------------- generic f16 MFMA GEMM, 64x64 tile ----------------
__global__ __launch_bounds__(256, 4) void gemm_f16_k(
    const f16* __restrict__ A, const f16* __restrict__ Bm, const float* __restrict__ bias,
    f16* __restrict__ C16, float* __restrict__ Cmu, float* __restrict__ Cls,
    int N, int K, int a_shift, int a_ostride, int a_t0,
    int mode, int o_t0, int tcshift)
{
  __shared__ __align__(16) f16 At[64][48];
  __shared__ __align__(16) f16 Bt[64][48];
  const int tid = threadIdx.x;
  const int mblk = blockIdx.x, nblk = blockIdx.y;
  const int w = tid >> 6, lane = tid & 63;

  const int sa_row = tid >> 2, sa_k = (tid & 3) * 8;
  const int m_g = mblk * 64 + sa_row;
  const long arow = (long)(m_g >> a_shift) * a_ostride + a_t0 + (m_g & ((1 << a_shift) - 1));
  const f16* aptr = A + arow * K + sa_k;
  const int sb_k = tid >> 3, sb_n = (tid & 7) * 8;
  const f16* bptr = Bm + (long)sb_k * N + nblk * 64 + sb_n;

  f4 acc[4];
#pragma unroll
  for (int i = 0; i < 4; ++i) acc[i] = (f4){0.f, 0.f, 0.f, 0.f};

  const int arow_l = w * 16 + (lane & 15);
  const int k0 = (lane >> 4) * 8;

  for (int kk = 0; kk < K; kk += 32) {
    uint4 av = *(const uint4*)(aptr + kk);
    uint4 bv = *(const uint4*)(bptr + (long)kk * N);
    __syncthreads();
    *(uint4*)&At[sa_row][sa_k] = av;
    h8 bx = __builtin_bit_cast(h8, bv);
#pragma unroll
    for (int j = 0; j < 8; ++j) Bt[sb_n + j][sb_k] = bx[j];
    __syncthreads();
    h8 af = *(const h8*)&At[arow_l][k0];
#pragma unroll
    for (int nt = 0; nt < 4; ++nt) {
      h8 bf = *(const h8*)&Bt[nt * 16 + (lane & 15)][k0];
      acc[nt] = __builtin_amdgcn_mfma_f32_16x16x32_f16(af, bf, acc[nt], 0, 0, 0);
    }
  }

  const int row_l = w * 16 + ((lane >> 4) << 2);
  const int col_l = lane & 15;
#pragma unroll
  for (int nt = 0; nt < 4; ++nt) {
    int gcol = nblk * 64 + nt * 16 + col_l;
    float bv = bias[gcol];
#pragma unroll
    for (int r = 0; r < 4; ++r) {
      int gm = mblk * 64 + row_l + r;
      float val = acc[nt][r] + bv;
      if (mode == 1) val = fmaxf(val, 0.f);
      if (mode <= 1) {
        C16[(long)gm * N + gcol] = (f16)val;
      } else {
        int bb = gm >> tcshift, tl = gm & ((1 << tcshift) - 1);
        long orow = (long)bb * Tt + o_t0 + tl;
        if (gcol < 64) Cmu[orow * 64 + gcol] = val;
        else Cls[orow * 64 + (gcol - 64)] = val;
      }
    }
  }
}

// ---------------- v512a scan: bigger reg head, LDS tail halved (chunk 0) ----
// r13-r17 established v512 is co-limited (VALU ~2470/SIMD, LDS ~2700/CU) and
// the 16 per-lane b128 weight-tail reads (~12 cyc each) dominate LDS. Move 32
// of those 64 tail-h2 into the register file (224+~30 working = 254 <= 256
// unified budget -> AGPR-park, not scratch): 8 fewer b128 reads/thread/step
// (-~770 LDS cyc/CU) for +32 accvgpr-reads (+~128 VALU cyc/SIMD).
__global__ void __launch_bounds__(512, 2) lstm512a_k(
    const f16* __restrict__ WhA, const f16* __restrict__ xp,
    f16* __restrict__ hout, float* __restrict__ c_state, f16* __restrict__ h_state,
    int TC, int first)
{
  const int b = blockIdx.x, tid = threadIdx.x;
  const int j = tid >> 1, odd = tid & 1;
  __shared__ __align__(16) h2 hbuf[2][128];
  __shared__ uint4 wt[8][512];               // tail k in [224,256): 64 KB

  h2 w[224];
  {
    const uint4* p4 = (const uint4*)(WhA + (long)tid * 512);
#pragma unroll
    for (int u = 0; u < 56; ++u) {
      uint4 v = p4[u];
      w[4 * u + 0] = bch2(v.x); w[4 * u + 1] = bch2(v.y);
      w[4 * u + 2] = bch2(v.z); w[4 * u + 3] = bch2(v.w);
    }
#pragma unroll
    for (int r = 0; r < 8; ++r) wt[r][tid] = p4[56 + r];
  }

  float c = first ? 0.f : c_state[b * Hh + j];
  if (tid < 128) {
    h2 hz = {(f16)0.f, (f16)0.f};
    hbuf[0][tid] = first ? hz : ((const h2*)h_state)[b * 128 + tid];
  }
  __syncthreads();

  const float sgn0 = odd ? 2.0f : -1.0f;
  const f16* xptr = xp + (long)b * TC * G4 + 2 * tid;  // quad-gate xp
  const f16* xend = xptr + (long)(TC - 1) * G4;
  h2 xv = *(const h2*)xptr;
  int p = 0;
  for (int t = 0; t < TC; ++t) {
    const f16* xnp = (xptr == xend) ? xptr : xptr + G4;
    h2 xn = *(const h2*)xnp;

    float a0 = (float)xv[0], b0 = 0.f, a1 = (float)xv[1], b1 = 0.f;
    const uint4* hb4 = (const uint4*)&hbuf[p][0];
#pragma unroll
    for (int i = 0; i < 28; ++i) {             // register head: k < 224
      uint4 hv = hb4[i];
      a0 = fdot2f(w[4 * i + 0], bch2(hv.x), a0);
      b0 = fdot2f(w[4 * i + 1], bch2(hv.y), b0);
      a0 = fdot2f(w[4 * i + 2], bch2(hv.z), a0);
      b0 = fdot2f(w[4 * i + 3], bch2(hv.w), b0);
      a1 = fdot2f(w[112 + 4 * i + 0], bch2(hv.x), a1);
      b1 = fdot2f(w[112 + 4 * i + 1], bch2(hv.y), b1);
      a1 = fdot2f(w[112 + 4 * i + 2], bch2(hv.z), a1);
      b1 = fdot2f(w[112 + 4 * i + 3], bch2(hv.w), b1);
    }
#pragma unroll
    for (int r = 0; r < 4; ++r) {              // LDS tail: k in [224,256)
      uint4 hv = hb4[28 + r];
      uint4 wa = wt[r][tid];
      uint4 wb = wt[4 + r][tid];
      a0 = fdot2f(bch2(wa.x), bch2(hv.x), a0);
      b0 = fdot2f(bch2(wa.y), bch2(hv.y), b0);
      a0 = fdot2f(bch2(wa.z), bch2(hv.z), a0);
      b0 = fdot2f(bch2(wa.w), bch2(hv.w), b0);
      a1 = fdot2f(bch2(wb.x), bch2(hv.x), a1);
      b1 = fdot2f(bch2(wb.y), bch2(hv.y), b1);
      a1 = fdot2f(bch2(wb.z), bch2(hv.z), a1);
      b1 = fdot2f(bch2(wb.w), bch2(hv.w), b1);
    }
    float A0 = a0 + b0, A1 = a1 + b1;

    float e0 = __expf(sgn0 * A0);
    float r0 = __builtin_amdgcn_rcpf(1.0f + e0);
    float act0 = odd ? 1.0f - 2.0f * r0 : r0;
    float e1 = __expf(-A1);
    float act1 = __builtin_amdgcn_rcpf(1.0f + e1);

    float px0 = qb<0xB1>(act0), px1 = qb<0xB1>(act1);
    float ai = odd ? px0 : act0;
    float af = odd ? px1 : act1;
    float ag = odd ? act0 : px0;
    float ao = odd ? act1 : px1;
    c = af * c + ai * ag;
    float hval = ao * tanhf_(c);
    if (!odd) {
      f16 hh = (f16)hval;
      ((f16*)&hbuf[p ^ 1][0])[j] = hh;
      hout[((long)b * TC + t) * Hh + j] = hh;
    }
    __syncthreads();
    p ^= 1;
    xv = xn;
    xptr = xnp;
  }
  if (!odd) c_state[b * Hh + j] = c;
  if (tid < 128) ((h2*)h_state)[b * 128 + tid] = hbuf[p][tid];
}

// ---------------- v512 scan (control, proven ~1447 us; chunk 1) -------------
__global__ void __launch_bounds__(512, 2) lstm512_k(
    const f16* __restrict__ WhT2, const f16* __restrict__ xp,
    f16* __restrict__ hout, float* __restrict__ c_state, f16* __restrict__ h_state,
    int TC, int first)
{
  const int b = blockIdx.x, tid = threadIdx.x;
  const int j = tid >> 1, odd = tid & 1;
  __shared__ __align__(16) h2 hbuf[2][128];
  __shared__ uint4 wt[16][512];

  h2 w[192];
  {
    const uint4* p4 = (const uint4*)(WhT2 + (long)tid * 512);
#pragma unroll
    for (int u = 0; u < 48; ++u) {
      uint4 v = p4[u];
      w[4 * u + 0] = bch2(v.x); w[4 * u + 1] = bch2(v.y);
      w[4 * u + 2] = bch2(v.z); w[4 * u + 3] = bch2(v.w);
    }
#pragma unroll
    for (int gg = 0; gg < 16; ++gg) wt[gg][tid] = p4[48 + gg];
  }

  float c = first ? 0.f : c_state[b * Hh + j];
  if (tid < 128) {
    h2 hz = {(f16)0.f, (f16)0.f};
    hbuf[0][tid] = first ? hz : ((const h2*)h_state)[b * 128 + tid];
  }
  __syncthreads();

  const float sgn0 = odd ? 2.0f : -1.0f;
  const f16* xptr = xp + (long)b * TC * G4 + 2 * tid;
  const f16* xend = xptr + (long)(TC - 1) * G4;
  h2 xv = *(const h2*)xptr;
  int p = 0;
  for (int t = 0; t < TC; ++t) {
    const f16* xnp = (xptr == xend) ? xptr : xptr + G4;
    h2 xn = *(const h2*)xnp;

    float a0 = (float)xv[0], b0 = 0.f, a1 = (float)xv[1], b1 = 0.f;
    const uint4* hb4 = (const uint4*)&hbuf[p][0];
#pragma unroll
    for (int i = 0; i < 24; ++i) {
      uint4 hv = hb4[i];
      a0 = fdot2f(w[4 * i + 0], bch2(hv.x), a0);
      b0 = fdot2f(w[4 * i + 1], bch2(hv.y), b0);
      a0 = fdot2f(w[4 * i + 2], bch2(hv.z), a0);
      b0 = fdot2f(w[4 * i + 3], bch2(hv.w), b0);
      a1 = fdot2f(w[96 + 4 * i + 0], bch2(hv.x), a1);
      b1 = fdot2f(w[96 + 4 * i + 1], bch2(hv.y), b1);
      a1 = fdot2f(w[96 + 4 * i + 2], bch2(hv.z), a1);
      b1 = fdot2f(w[96 + 4 * i + 3], bch2(hv.w), b1);
    }
#pragma unroll
    for (int gg = 0; gg < 8; ++gg) {
      uint4 hv = hb4[24 + gg];
      uint4 wa = wt[gg][tid];
      uint4 wb = wt[8 + gg][tid];
      a0 = fdot2f(bch2(wa.x), bch2(hv.x), a0);
      b0 = fdot2f(bch2(wa.y), bch2(hv.y), b0);
      a0 = fdot2f(bch2(wa.z), bch2(hv.z), a0);
      b0 = fdot2f(bch2(wa.w), bch2(hv.w), b0);
      a1 = fdot2f(bch2(wb.x), bch2(hv.x), a1);
      b1 = fdot2f(bch2(wb.y), bch2(hv.y), b1);
      a1 = fdot2f(bch2(wb.z), bch2(hv.z), a1);
      b1 = fdot2f(bch2(wb.w), bch2(hv.w), b1);
    }
    float A0 = a0 + b0, A1 = a1 + b1;

    float e0 = __expf(sgn0 * A0);
    float r0 = __builtin_amdgcn_rcpf(1.0f + e0);
    float act0 = odd ? 1.0f - 2.0f * r0 : r0;
    float e1 = __expf(-A1);
    float act1 = __builtin_amdgcn_rcpf(1.0f + e1);

    float px0 = qb<0xB1>(act0), px1 = qb<0xB1>(act1);
    float ai = odd ? px0 : act0;
    float af = odd ? px1 : act1;
    float ag = odd ? act0 : px0;
    float ao = odd ? act1 : px1;
    c = af * c + ai * ag;
    float hval = ao * tanhf_(c);
    if (!odd) {
      f16 hh = (f16)hval;
      ((f16*)&hbuf[p ^ 1][0])[j] = hh;
      hout[((long)b * TC + t) * Hh + j] = hh;
    }
    __syncthreads();
    p ^= 1;
    xv = xn;
    xptr = xnp;
  }
  if (!odd) c_state[b * Hh + j] = c;
  if (tid < 128) ((h2*)h_state)[b * 128 + tid] = hbuf[p][tid];
}

// ---------------- host ----------------
extern "C" void kernel_launch(void* const* d_in, const int* in_sizes, int n_in,
                              void* d_out, int out_size, void* d_ws, size_t ws_size,
                              hipStream_t stream)
{
  const float* x  = (const float*)d_in[0];
  const float* Wi = (const float*)d_in[1];
  const float* Wh = (const float*)d_in[2];
  const float* bh = (const float*)d_in[3];
  const float* W1 = (const float*)d_in[4];
  const float* b1 = (const float*)d_in[5];
  const float* W2 = (const float*)d_in[6];
  const float* b2 = (const float*)d_in[7];
  float* out = (float*)d_out;

  char* ws = (char*)d_ws;
  size_t off = 0;
  auto alloc = [&](size_t bytes) -> char* {
    char* p = ws + off;
    off = (off + bytes + 255) & ~(size_t)255;
    return p;
  };
  f16* x16    = (f16*)alloc((size_t)Bb * Tt * Xx * 2);
  f16* wi16p  = (f16*)alloc((size_t)Xx * G4 * 2);
  float* bhp  = (float*)alloc((size_t)G4 * 4);
  f16* whT2   = (f16*)alloc((size_t)G4 * Hh * 2);
  f16* whA    = (f16*)alloc((size_t)G4 * Hh * 2);
  f16* w116   = (f16*)alloc((size_t)Hh * Hh * 2);
  f16* w216   = (f16*)alloc((size_t)Hh * Z2 * 2);
  float* cst  = (float*)alloc((size_t)Bb * Hh * 4);
  f16* hst    = (f16*)alloc((size_t)Bb * Hh * 2);

  int tc = 1024;  // 2 chunks: chunk0 = big-reg-head experiment, chunk1 = control
  while (tc > 32) {
    size_t need = (size_t)Bb * tc * G4 * 2 + (size_t)Bb * tc * Hh * 2;
    if (off + need <= ws_size) break;
    tc >>= 1;
  }
  int tcsh = __builtin_ctz((unsigned)tc);
  f16* xp16 = (f16*)alloc((size_t)Bb * tc * G4 * 2);
  f16* h16  = (f16*)alloc((size_t)Bb * tc * Hh * 2);
  f16* hid16 = xp16;  // head hidden aliases xp (xp fully consumed by the scan)

  cast_f16_k<<<(Bb * Tt * Xx) / 1024, 256, 0, stream>>>(x, x16, Bb * Tt * Xx);
  cast_wiP_k<<<(Xx * G4) / 256, 256, 0, stream>>>(Wi, wi16p);
  cast_bhp_k<<<4, 256, 0, stream>>>(bh, bhp);
  cast_f16_k<<<(Hh * Hh) / 1024, 256, 0, stream>>>(W1, w116, Hh * Hh);
  cast_f16_k<<<(Hh * Z2) / 1024, 256, 0, stream>>>(W2, w216, Hh * Z2);
  cast_whT2_k<<<(Hh * G4) / 256, 256, 0, stream>>>(Wh, whT2);
  cast_whA_k<<<(Hh * G4) / 256, 256, 0, stream>>>(Wh, whA);

  float* mu = out;
  float* ls = out + (size_t)Bb * Tt * 64;

  int ci = 0;
  for (int t0 = 0; t0 < Tt; t0 += tc, ++ci) {
    dim3 gx(Bb * tc / 64, G4 / 64);
    gemm_f16_k<<<gx, 256, 0, stream>>>(x16, wi16p, bhp, xp16, nullptr, nullptr,
                                       G4, Xx, tcsh, Tt, t0, 0, 0, 0);
    if (ci == 0)
      lstm512a_k<<<Bb, 512, 0, stream>>>(whA, xp16, h16, cst, hst, tc, (t0 == 0) ? 1 : 0);
    else
      lstm512_k<<<Bb, 512, 0, stream>>>(whT2, xp16, h16, cst, hst, tc, (t0 == 0) ? 1 : 0);
    dim3 g1g(Bb * tc / 64, Hh / 64);
    gemm_f16_k<<<g1g, 256, 0, stream>>>(h16, w116, b1, hid16, nullptr, nullptr,
                                        Hh, Hh, 30, 0, 0, 1, 0, 0);
    dim3 g2g(Bb * tc / 64, Z2 / 64);
    gemm_f16_k<<<g2g, 256, 0, stream>>>(hid16, w216, b2, nullptr, mu, ls,
                                        Z2, Hh, 30, 0, 0, 2, t0, tcsh);
  }
}

// Round 19
// 3125.493 us; speedup vs baseline: 1.1328x; 1.1328x over previous
//
#include <hip/hip_runtime.h>

typedef _Float16 f16;
typedef _Float16 h2 __attribute__((ext_vector_type(2)));
typedef _Float16 h8 __attribute__((ext_vector_type(8)));
typedef float f4 __attribute__((ext_vector_type(4)));

constexpr int Bb = 64, Tt = 2048, Xx = 128, Hh = 256, G4 = 1024, Z2 = 128;

__device__ __forceinline__ float fdot2f(h2 a, h2 b, float c) {
#if __has_builtin(__builtin_amdgcn_fdot2)
  return __builtin_amdgcn_fdot2(a, b, c, false);
#else
  return c + (float)a[0] * (float)b[0] + (float)a[1] * (float)b[1];
#endif
}
__device__ __forceinline__ float tanhf_(float x) {
  float e = __expf(2.0f * x);
  return 1.0f - 2.0f * __builtin_amdgcn_rcpf(e + 1.0f);
}
__device__ __forceinline__ h2 bch2(unsigned int u) { return __builtin_bit_cast(h2, u); }

template <int CTRL>
__device__ __forceinline__ float qb(float v) {  // quad_perm shuffle
  return __builtin_bit_cast(float,
      __builtin_amdgcn_mov_dpp(__builtin_bit_cast(int, v), CTRL, 0xf, 0xf, true));
}

// ---------------- casts ----------------
__global__ void cast_f16_k(const float* __restrict__ in, f16* __restrict__ out, int n) {
  int i = (blockIdx.x * 256 + threadIdx.x) * 4;
  if (i >= n) return;
  float4 v = *(const float4*)(in + i);
  h2 a = {(f16)v.x, (f16)v.y};
  h2 b = {(f16)v.z, (f16)v.w};
  uint2 o = {__builtin_bit_cast(unsigned int, a), __builtin_bit_cast(unsigned int, b)};
  *(uint2*)(out + i) = o;
}

// Wi columns permuted to quad-gate order col' = 4j+g (orig col = g*256+j):
// xp then holds the 4 gate pre-activations of unit j contiguously, so the
// v512 scan loads its 2 gate pre-activations as one dword at 2*tid.
__global__ void cast_wiP_k(const float* __restrict__ Wi, f16* __restrict__ out) {
  int idx = blockIdx.x * 256 + threadIdx.x;  // 131072 = 128*1024
  int k = idx >> 10, cp = idx & 1023;
  out[idx] = (f16)Wi[(long)k * G4 + (cp & 3) * 256 + (cp >> 2)];
}
__global__ void cast_bhp_k(const float* __restrict__ bh, float* __restrict__ bhp) {
  int cp = blockIdx.x * 256 + threadIdx.x;   // 1024
  bhp[cp] = bh[(cp & 3) * 256 + (cp >> 2)];
}

// v512-layout: thread tid owns packed cols c0=2tid, c1=2tid+1 (cc -> gate cc&3,
// unit cc>>2). Slots: [0,96) c0 k<192; [96,192) c1 k<192; [192,224) c0 tail;
// [224,256) c1 tail.  (Empirical optimum of the reg/LDS split: r18 showed
// moving tail h2 into regs regresses via the AGPR-read tax; r11 showed
// streaming it from L2 regresses via latency.)
__global__ void cast_whT2_k(const float* __restrict__ Wh, f16* __restrict__ WhT2) {
  int idx = blockIdx.x * 256 + threadIdx.x;  // 262144 = 512 threads * 512 f16
  int tid = idx >> 9, f = idx & 511;
  int s = f >> 1, e = f & 1;
  int c_off, k;
  if (s < 96)      { c_off = 0; k = 2 * s + e; }
  else if (s < 192){ c_off = 1; k = 2 * (s - 96) + e; }
  else if (s < 224){ c_off = 0; k = 192 + 2 * (s - 192) + e; }
  else             { c_off = 1; k = 192 + 2 * (s - 224) + e; }
  int cc = 2 * tid + c_off;
  int j = cc >> 2, g = cc & 3;
  WhT2[(long)tid * 512 + f] = (f16)Wh[(long)k * G4 + g * 256 + j];
}

// ---------------- generic f16 MFMA GEMM, 64x64 tile ----------------
__global__ __launch_bounds__(256, 4) void gemm_f16_k(
    const f16* __restrict__ A, const f16* __restrict__ Bm, const float* __restrict__ bias,
    f16* __restrict__ C16, float* __restrict__ Cmu, float* __restrict__ Cls,
    int N, int K, int a_shift, int a_ostride, int a_t0,
    int mode, int o_t0, int tcshift)
{
  __shared__ __align__(16) f16 At[64][48];
  __shared__ __align__(16) f16 Bt[64][48];
  const int tid = threadIdx.x;
  const int mblk = blockIdx.x, nblk = blockIdx.y;
  const int w = tid >> 6, lane = tid & 63;

  const int sa_row = tid >> 2, sa_k = (tid & 3) * 8;
  const int m_g = mblk * 64 + sa_row;
  const long arow = (long)(m_g >> a_shift) * a_ostride + a_t0 + (m_g & ((1 << a_shift) - 1));
  const f16* aptr = A + arow * K + sa_k;
  const int sb_k = tid >> 3, sb_n = (tid & 7) * 8;
  const f16* bptr = Bm + (long)sb_k * N + nblk * 64 + sb_n;

  f4 acc[4];
#pragma unroll
  for (int i = 0; i < 4; ++i) acc[i] = (f4){0.f, 0.f, 0.f, 0.f};

  const int arow_l = w * 16 + (lane & 15);
  const int k0 = (lane >> 4) * 8;

  for (int kk = 0; kk < K; kk += 32) {
    uint4 av = *(const uint4*)(aptr + kk);
    uint4 bv = *(const uint4*)(bptr + (long)kk * N);
    __syncthreads();
    *(uint4*)&At[sa_row][sa_k] = av;
    h8 bx = __builtin_bit_cast(h8, bv);
#pragma unroll
    for (int j = 0; j < 8; ++j) Bt[sb_n + j][sb_k] = bx[j];
    __syncthreads();
    h8 af = *(const h8*)&At[arow_l][k0];
#pragma unroll
    for (int nt = 0; nt < 4; ++nt) {
      h8 bf = *(const h8*)&Bt[nt * 16 + (lane & 15)][k0];
      acc[nt] = __builtin_amdgcn_mfma_f32_16x16x32_f16(af, bf, acc[nt], 0, 0, 0);
    }
  }

  const int row_l = w * 16 + ((lane >> 4) << 2);
  const int col_l = lane & 15;
#pragma unroll
  for (int nt = 0; nt < 4; ++nt) {
    int gcol = nblk * 64 + nt * 16 + col_l;
    float bv = bias[gcol];
#pragma unroll
    for (int r = 0; r < 4; ++r) {
      int gm = mblk * 64 + row_l + r;
      float val = acc[nt][r] + bv;
      if (mode == 1) val = fmaxf(val, 0.f);
      if (mode <= 1) {
        C16[(long)gm * N + gcol] = (f16)val;
      } else {
        int bb = gm >> tcshift, tl = gm & ((1 << tcshift) - 1);
        long orow = (long)bb * Tt + o_t0 + tl;
        if (gcol < 64) Cmu[orow * 64 + gcol] = val;
        else Cls[orow * 64 + (gcol - 64)] = val;
      }
    }
  }
}

// ---------------- v512 scan (best-known: ~1447 us/chunk, both chunks) -------
// 512 thr = 2 waves/SIMD (256-reg unified budget). Thread owns packed cols
// 2tid (even: gates i,f of unit tid>>1) and 2tid+1 (odd: g,o); pair exchange
// via one dpp; 1 barrier/step via double-buffered hbuf. 192 reg-h2 + 16
// per-lane b128 LDS-tail reads is the measured optimum split (r11/r18).
__global__ void __launch_bounds__(512, 2) lstm512_k(
    const f16* __restrict__ WhT2, const f16* __restrict__ xp,
    f16* __restrict__ hout, float* __restrict__ c_state, f16* __restrict__ h_state,
    int TC, int first)
{
  const int b = blockIdx.x, tid = threadIdx.x;
  const int j = tid >> 1, odd = tid & 1;
  __shared__ __align__(16) h2 hbuf[2][128];
  __shared__ uint4 wt[16][512];

  h2 w[192];
  {
    const uint4* p4 = (const uint4*)(WhT2 + (long)tid * 512);
#pragma unroll
    for (int u = 0; u < 48; ++u) {
      uint4 v = p4[u];
      w[4 * u + 0] = bch2(v.x); w[4 * u + 1] = bch2(v.y);
      w[4 * u + 2] = bch2(v.z); w[4 * u + 3] = bch2(v.w);
    }
#pragma unroll
    for (int gg = 0; gg < 16; ++gg) wt[gg][tid] = p4[48 + gg];
  }

  float c = first ? 0.f : c_state[b * Hh + j];
  if (tid < 128) {
    h2 hz = {(f16)0.f, (f16)0.f};
    hbuf[0][tid] = first ? hz : ((const h2*)h_state)[b * 128 + tid];
  }
  __syncthreads();

  const float sgn0 = odd ? 2.0f : -1.0f;
  const f16* xptr = xp + (long)b * TC * G4 + 2 * tid;   // quad-gate xp order
  const f16* xend = xptr + (long)(TC - 1) * G4;
  h2 xv = *(const h2*)xptr;
  int p = 0;
  for (int t = 0; t < TC; ++t) {
    const f16* xnp = (xptr == xend) ? xptr : xptr + G4;
    h2 xn = *(const h2*)xnp;

    float a0 = (float)xv[0], b0 = 0.f, a1 = (float)xv[1], b1 = 0.f;
    const uint4* hb4 = (const uint4*)&hbuf[p][0];
#pragma unroll
    for (int i = 0; i < 24; ++i) {
      uint4 hv = hb4[i];
      a0 = fdot2f(w[4 * i + 0], bch2(hv.x), a0);
      b0 = fdot2f(w[4 * i + 1], bch2(hv.y), b0);
      a0 = fdot2f(w[4 * i + 2], bch2(hv.z), a0);
      b0 = fdot2f(w[4 * i + 3], bch2(hv.w), b0);
      a1 = fdot2f(w[96 + 4 * i + 0], bch2(hv.x), a1);
      b1 = fdot2f(w[96 + 4 * i + 1], bch2(hv.y), b1);
      a1 = fdot2f(w[96 + 4 * i + 2], bch2(hv.z), a1);
      b1 = fdot2f(w[96 + 4 * i + 3], bch2(hv.w), b1);
    }
#pragma unroll
    for (int gg = 0; gg < 8; ++gg) {
      uint4 hv = hb4[24 + gg];
      uint4 wa = wt[gg][tid];
      uint4 wb = wt[8 + gg][tid];
      a0 = fdot2f(bch2(wa.x), bch2(hv.x), a0);
      b0 = fdot2f(bch2(wa.y), bch2(hv.y), b0);
      a0 = fdot2f(bch2(wa.z), bch2(hv.z), a0);
      b0 = fdot2f(bch2(wa.w), bch2(hv.w), b0);
      a1 = fdot2f(bch2(wb.x), bch2(hv.x), a1);
      b1 = fdot2f(bch2(wb.y), bch2(hv.y), b1);
      a1 = fdot2f(bch2(wb.z), bch2(hv.z), a1);
      b1 = fdot2f(bch2(wb.w), bch2(hv.w), b1);
    }
    float A0 = a0 + b0, A1 = a1 + b1;

    float e0 = __expf(sgn0 * A0);
    float r0 = __builtin_amdgcn_rcpf(1.0f + e0);
    float act0 = odd ? 1.0f - 2.0f * r0 : r0;
    float e1 = __expf(-A1);
    float act1 = __builtin_amdgcn_rcpf(1.0f + e1);

    float px0 = qb<0xB1>(act0), px1 = qb<0xB1>(act1);
    float ai = odd ? px0 : act0;
    float af = odd ? px1 : act1;
    float ag = odd ? act0 : px0;
    float ao = odd ? act1 : px1;
    c = af * c + ai * ag;
    float hval = ao * tanhf_(c);
    if (!odd) {
      f16 hh = (f16)hval;
      ((f16*)&hbuf[p ^ 1][0])[j] = hh;
      hout[((long)b * TC + t) * Hh + j] = hh;
    }
    __syncthreads();
    p ^= 1;
    xv = xn;
    xptr = xnp;
  }
  if (!odd) c_state[b * Hh + j] = c;
  if (tid < 128) ((h2*)h_state)[b * 128 + tid] = hbuf[p][tid];
}

// ---------------- host ----------------
extern "C" void kernel_launch(void* const* d_in, const int* in_sizes, int n_in,
                              void* d_out, int out_size, void* d_ws, size_t ws_size,
                              hipStream_t stream)
{
  const float* x  = (const float*)d_in[0];
  const float* Wi = (const float*)d_in[1];
  const float* Wh = (const float*)d_in[2];
  const float* bh = (const float*)d_in[3];
  const float* W1 = (const float*)d_in[4];
  const float* b1 = (const float*)d_in[5];
  const float* W2 = (const float*)d_in[6];
  const float* b2 = (const float*)d_in[7];
  float* out = (float*)d_out;

  char* ws = (char*)d_ws;
  size_t off = 0;
  auto alloc = [&](size_t bytes) -> char* {
    char* p = ws + off;
    off = (off + bytes + 255) & ~(size_t)255;
    return p;
  };
  f16* x16    = (f16*)alloc((size_t)Bb * Tt * Xx * 2);
  f16* wi16p  = (f16*)alloc((size_t)Xx * G4 * 2);
  float* bhp  = (float*)alloc((size_t)G4 * 4);
  f16* whT2   = (f16*)alloc((size_t)G4 * Hh * 2);
  f16* w116   = (f16*)alloc((size_t)Hh * Hh * 2);
  f16* w216   = (f16*)alloc((size_t)Hh * Z2 * 2);
  float* cst  = (float*)alloc((size_t)Bb * Hh * 4);
  f16* hst    = (f16*)alloc((size_t)Bb * Hh * 2);

  int tc = 1024;
  while (tc > 32) {
    size_t need = (size_t)Bb * tc * G4 * 2 + (size_t)Bb * tc * Hh * 2;
    if (off + need <= ws_size) break;
    tc >>= 1;
  }
  int tcsh = __builtin_ctz((unsigned)tc);
  f16* xp16 = (f16*)alloc((size_t)Bb * tc * G4 * 2);
  f16* h16  = (f16*)alloc((size_t)Bb * tc * Hh * 2);
  f16* hid16 = xp16;  // head hidden aliases xp (xp fully consumed by the scan)

  cast_f16_k<<<(Bb * Tt * Xx) / 1024, 256, 0, stream>>>(x, x16, Bb * Tt * Xx);
  cast_wiP_k<<<(Xx * G4) / 256, 256, 0, stream>>>(Wi, wi16p);
  cast_bhp_k<<<4, 256, 0, stream>>>(bh, bhp);
  cast_f16_k<<<(Hh * Hh) / 1024, 256, 0, stream>>>(W1, w116, Hh * Hh);
  cast_f16_k<<<(Hh * Z2) / 1024, 256, 0, stream>>>(W2, w216, Hh * Z2);
  cast_whT2_k<<<(Hh * G4) / 256, 256, 0, stream>>>(Wh, whT2);

  float* mu = out;
  float* ls = out + (size_t)Bb * Tt * 64;

  for (int t0 = 0; t0 < Tt; t0 += tc) {
    dim3 gx(Bb * tc / 64, G4 / 64);
    gemm_f16_k<<<gx, 256, 0, stream>>>(x16, wi16p, bhp, xp16, nullptr, nullptr,
                                       G4, Xx, tcsh, Tt, t0, 0, 0, 0);
    lstm512_k<<<Bb, 512, 0, stream>>>(whT2, xp16, h16, cst, hst, tc, (t0 == 0) ? 1 : 0);
    dim3 g1g(Bb * tc / 64, Hh / 64);
    gemm_f16_k<<<g1g, 256, 0, stream>>>(h16, w116, b1, hid16, nullptr, nullptr,
                                        Hh, Hh, 30, 0, 0, 1, 0, 0);
    dim3 g2g(Bb * tc / 64, Z2 / 64);
    gemm_f16_k<<<g2g, 256, 0, stream>>>(hid16, w216, b2, nullptr, mu, ls,
                                        Z2, Hh, 30, 0, 0, 2, t0, tcsh);
  }
}